// Round 11
// baseline (327.135 us; speedup 1.0000x reference)
//
#include <hip/hip_runtime.h>
#include <hip/hip_bf16.h>
#include <cstdint>
#include <cstddef>

#define S_LEN 4096
#define HDIM  512
#define BDIM  8
#define DIN   256
#define NLAYER 2

using float4v = __attribute__((ext_vector_type(4))) float;
using short8  = __attribute__((ext_vector_type(8))) short;
using bf16x8  = __attribute__((ext_vector_type(8))) __bf16;

struct __align__(8) us4_t { unsigned short x, y, z, w; };

// native bf16 cast: single v_cvt_pk_bf16_f32 (RNE), compiler-selected.
__device__ __forceinline__ unsigned short f2bf(float f) {
    return __builtin_bit_cast(unsigned short, (__bf16)f);
}
__device__ __forceinline__ float bf2f(unsigned short s) {
    union { unsigned u; float f; } v; v.u = ((unsigned)s) << 16;
    return v.f;
}
// hardware-approx rcp/rsq (~1 ulp): outputs are bf16-rounded downstream, and
// inputs are bounded away from the edge cases (rcp arg >= 1, rsq arg >= 1e-5).
__device__ __forceinline__ float fast_rcp(float x) { return __builtin_amdgcn_rcpf(x); }
__device__ __forceinline__ float fast_rsq(float x) { return __builtin_amdgcn_rsqf(x); }

// 16x16x32: 16 rows/fragment-read -> free 2-way LDS aliasing with the 8-slot
// XOR swizzle. (R4: 32x32x16 pigeonholes 4 rows/slot -> 5.5M conflicts.
// R8: single-buffer 4-block occupancy loses to dbuf counted-vmcnt 2-block.
// R10: NW=8 at the SAME dbuf schedule = +10% kvr — the kernels were
// latency-bound at 2 waves/SIMD; more waves at fixed schedule is the fix.)
__device__ __forceinline__ float4v mfma_bf16(short8 a, short8 b, float4v c) {
    return __builtin_amdgcn_mfma_f32_16x16x32_bf16(
        __builtin_bit_cast(bf16x8, a), __builtin_bit_cast(bf16x8, b), c, 0, 0, 0);
}
__device__ __forceinline__ float wave_sum(float v) {
#pragma unroll
    for (int m = 1; m < 64; m <<= 1) v += __shfl_xor(v, m, 64);
    return v;
}
// async global->LDS, 16B per lane. LDS dest is wave-uniform base + lane*16.
__device__ __forceinline__ void gload16(const void* g, void* l) {
    __builtin_amdgcn_global_load_lds(
        (const __attribute__((address_space(1))) unsigned int*)g,
        (__attribute__((address_space(3))) unsigned int*)l,
        16, 0, 0);
}

// counted vmcnt wait + raw barrier (T4: never drain to 0 in steady state)
#define VMW_ASM(N) asm volatile("s_waitcnt vmcnt(" #N ")" ::: "memory")
template<int N> __device__ __forceinline__ void vmwait() {
    static_assert(N == 0 || N == 4 || N == 5 || N == 6 || N == 8 || N == 10,
                  "add a case for this N");
    if constexpr (N == 0) VMW_ASM(0);
    else if constexpr (N == 4) VMW_ASM(4);
    else if constexpr (N == 5) VMW_ASM(5);
    else if constexpr (N == 6) VMW_ASM(6);
    else if constexpr (N == 8) VMW_ASM(8);
    else if constexpr (N == 10) VMW_ASM(10);
}
#define LGKM0()    asm volatile("s_waitcnt lgkmcnt(0)" ::: "memory")
#define RBARRIER() asm volatile("s_barrier" ::: "memory")

// merged f32 -> bf16 conversion for three tensors (x, Win, Wo) in one launch
__global__ void cvt3_k(const float* __restrict__ a, unsigned short* __restrict__ oa, int na4,
                       const float* __restrict__ b, unsigned short* __restrict__ ob, int nb4,
                       const float* __restrict__ c, unsigned short* __restrict__ oc2, int nc4)
{
    int i = blockIdx.x * blockDim.x + threadIdx.x;
    const float* src; unsigned short* dst; int idx;
    if (i < na4)             { src = a; dst = oa;  idx = i; }
    else if (i < na4 + nb4)  { src = b; dst = ob;  idx = i - na4; }
    else if (i < na4 + nb4 + nc4) { src = c; dst = oc2; idx = i - na4 - nb4; }
    else return;
    float4 v = ((const float4*)src)[idx];
    us4_t o;
    o.x = f2bf(v.x); o.y = f2bf(v.y); o.z = f2bf(v.z); o.w = f2bf(v.w);
    ((us4_t*)dst)[idx] = o;
}

// folded weights: Wf[l][j][o][k] = bf16( W_j[l][o][k] * t_j[l][k] ), j in {k,v,r}
__global__ void cvtw_k(const float* __restrict__ Wk, const float* __restrict__ Wv,
                       const float* __restrict__ Wr,
                       const float* __restrict__ tmk, const float* __restrict__ tmv,
                       const float* __restrict__ tmr,
                       unsigned short* __restrict__ Wf)
{
    int i = blockIdx.x * blockDim.x + threadIdx.x;       // element-quad index
    int e = i * 4;
    if (e >= NLAYER * 3 * HDIM * HDIM) return;
    const int HH = HDIM * HDIM;
    int l   = (e >= 3 * HH) ? 1 : 0;
    int rem = e - l * 3 * HH;
    int j   = rem >> 18;                                  // / (512*512)
    int ok  = rem & (HH - 1);
    int k   = ok & (HDIM - 1);
    const float* W = (j == 0) ? Wk : (j == 1) ? Wv : Wr;
    const float* t = (j == 0) ? tmk : (j == 1) ? tmv : tmr;
    float4 w = *(const float4*)(W + (size_t)l * HH + ok);
    const float* tp = t + l * HDIM + k;
    us4_t o;
    o.x = f2bf(w.x * tp[0]); o.y = f2bf(w.y * tp[1]);
    o.z = f2bf(w.z * tp[2]); o.w = f2bf(w.w * tp[3]);
    *(us4_t*)(Wf + e) = o;
}

// mb[j][b][o] = sum_k (1 - t_j[k]) * mean[b,k] * W_j[o,k]   (f32 weights)
__global__ void meanbias_k(const float* __restrict__ msum_l, float invS,
    const float* __restrict__ Wk, const float* __restrict__ Wv, const float* __restrict__ Wr,
    const float* __restrict__ tmk, const float* __restrict__ tmv, const float* __restrict__ tmr,
    float* __restrict__ mb)
{
    __shared__ float m2[HDIM];
    const int j = blockIdx.x, b = blockIdx.y, oc = blockIdx.z;  // (3, 8, 8)
    const int tid = threadIdx.x, lane = tid & 63, wid = tid >> 6;
    const float* W = (j == 0) ? Wk : (j == 1) ? Wv : Wr;
    const float* t = (j == 0) ? tmk : (j == 1) ? tmv : tmr;
    for (int i = tid; i < HDIM; i += 256)
        m2[i] = msum_l[b * HDIM + i] * invS * (1.f - t[i]);
    __syncthreads();
    const int o0 = oc * 64 + wid * 16;
    for (int oo = 0; oo < 16; oo++) {
        int o = o0 + oo;
        const float* wr_ = W + (size_t)o * HDIM + lane * 8;
        float4 w0 = *(const float4*)wr_;
        float4 w1 = *(const float4*)(wr_ + 4);
        const float* mp = m2 + lane * 8;
        float s = w0.x * mp[0] + w0.y * mp[1] + w0.z * mp[2] + w0.w * mp[3]
                + w1.x * mp[4] + w1.y * mp[5] + w1.z * mp[6] + w1.w * mp[7];
        s = wave_sum(s);
        if (lane == 0) mb[((size_t)j * BDIM + b) * HDIM + o] = s;
    }
}

// ---------------------------------------------------------------------------
// bf16 MFMA GEMM: out_j[m,o] = sum_k A[m,k] * B_j[o,k], all operands bf16.
// Staging: global_load_lds width-16, double-buffered LDS, XOR-swizzled
// (source pre-swizzle + swizzled read, linear LDS dest).
// Counted-vmcnt pipeline: raw s_barrier + s_waitcnt vmcnt(NCW) — exactly the
// own-tile loads retire; the next tile's NCW loads stay in flight.
// 2 blocks/CU; 1D grid, XCD-chunked mapping, col-fastest logical order.
// NW = waves/block = 8 everywhere (R10/R11): 4 waves/SIMD at the SAME
// schedule/tiles/staging — the GEMMs were latency-bound at 2 waves/SIMD.
// Wave (wr, wc) grid: 2 x (NW/2); per-wave tile TM/2 x BN/(NW/2) per mat.
// Epilogues stage the output tile in LDS and write fully-coalesced dwordx4.
// EPI 1 sigmoids use v_rcp_f32; f32->bf16 via native cast (v_cvt_pk_bf16_f32).
// EPI 0: +bias -> bf16 out + per-(b,col) colsum atomics (input proj)
// EPI 1: kvr fused: s = relu(v+mbv)*sigmoid(relu(k+mbk)); r = sigmoid(.+mbr)
// EPI 3: plain bf16 out (Wo proj)
// ---------------------------------------------------------------------------
template<int TM, int BN, int NMAT, int EPI, int K, int NY, int NW>
__global__ __launch_bounds__(NW * 64, 2) void gemm2_k(
    const unsigned short* __restrict__ A,
    const unsigned short* __restrict__ B0,
    const unsigned short* __restrict__ B1,
    const unsigned short* __restrict__ B2,
    const float* __restrict__ mb,          // EPI=0: bias[512]; EPI=1: [3][8][512]
    unsigned short* __restrict__ outB0,
    unsigned short* __restrict__ outB1,
    float* __restrict__ msum_out)
{
    constexpr int NTHR = NW * 64;
    constexpr int NT   = K / 64;
    static_assert(NT >= 2, "pipeline needs >=2 K-tiles");
    constexpr int ROWS = TM + NMAT * BN;    // 128B rows per buffer
    constexpr int NC   = ROWS / 8;          // 1KB chunks
    static_assert(NC % NW == 0, "chunks must split evenly across waves");
    constexpr int NCW  = NC / NW;           // chunks per wave (= loads in flight/stage)
    constexpr int WC   = NW / 2;            // waves along cols
    constexpr int MI   = TM / 32;           // row frags per wave (TM/2 rows)
    constexpr int CW   = BN / WC;           // cols per wave per mat
    constexpr int NI   = CW / 16;           // col frags per wave per mat
    static_assert(NI >= 1, "");
    __shared__ __align__(16) unsigned short smem[2][ROWS * 64];
    static_assert((EPI == 1 ? 2 : 1) * TM * (BN + 8) <= 2 * ROWS * 64,
                  "epilogue overflow");

    const int tid = threadIdx.x, lane = tid & 63, wid = tid >> 6;
    const int wr = wid / WC, wc = wid % WC;
    // XCD-chunked bijective remap (gridDim.x % 8 == 0), col-fastest logical
    const int chunk = gridDim.x >> 3;
    const int logical = (blockIdx.x & 7) * chunk + (blockIdx.x >> 3);
    const int m0 = (logical / NY) * TM, n0 = (logical % NY) * BN;

    // per-chunk global pointers (source pre-swizzled: slot' = (lane&7) ^ (lane>>3))
    const int l8 = lane >> 3;
    const int soff = (((lane & 7) ^ l8) * 16);
    const char* gp[NCW];
#pragma unroll
    for (int i = 0; i < NCW; i++) {
        int c = wid * NCW + i;
        const unsigned short* base; int row;
        if (c < TM / 8) { base = A; row = m0 + c * 8 + l8; }
        else {
            int cb = c - TM / 8;
            int j  = cb / (BN / 8);
            int rl = (cb % (BN / 8)) * 8 + l8;
            base = (j == 0) ? B0 : ((j == 1) ? B1 : B2);
            row  = n0 + rl;
        }
        gp[i] = (const char*)base + (size_t)row * (K * 2) + soff;
    }

    float4v acc[NMAT][MI][NI];
#pragma unroll
    for (int j = 0; j < NMAT; j++)
#pragma unroll
        for (int mi = 0; mi < MI; mi++)
#pragma unroll
            for (int ni = 0; ni < NI; ni++)
                acc[j][mi][ni] = (float4v){0.f, 0.f, 0.f, 0.f};

    auto STAGE = [&](int buf) {
#pragma unroll
        for (int i = 0; i < NCW; i++) {
            gload16(gp[i], (char*)&smem[buf][0] + (unsigned)(wid * NCW + i) * 1024);
            gp[i] += 128;                               // advance one K-step (64 bf16)
        }
    };

    STAGE(0);                                           // tile 0 -> buf0
    STAGE(1);                                           // tile 1 -> buf1
    for (int t = 0; t < NT; t++) {
        // own stage(t) loads retired (in-order); stage(t+1) stays in flight
        if (t == NT - 1) vmwait<0>(); else vmwait<NCW>();
        RBARRIER();                                     // all waves: tile t landed
        const int cur = t & 1;
        const unsigned short* As = &smem[cur][0];
        const unsigned short* Bs = &smem[cur][TM * 64];
#pragma unroll
        for (int kk = 0; kk < 2; kk++) {
            short8 a_[MI];
#pragma unroll
            for (int mi = 0; mi < MI; mi++) {
                int row = wr * (TM / 2) + mi * 16 + (lane & 15);
                int sl  = (kk * 4 + (lane >> 4)) ^ (row & 7);
                a_[mi] = *(const short8*)&As[row * 64 + sl * 8];
            }
#pragma unroll
            for (int ni = 0; ni < NI; ni++) {
                int rowb = wc * CW + ni * 16 + (lane & 15);
                int slb  = (kk * 4 + (lane >> 4)) ^ (rowb & 7);
#pragma unroll
                for (int j = 0; j < NMAT; j++) {
                    short8 b_ = *(const short8*)&Bs[(j * BN + rowb) * 64 + slb * 8];
#pragma unroll
                    for (int mi = 0; mi < MI; mi++)
                        acc[j][mi][ni] = mfma_bf16(a_[mi], b_, acc[j][mi][ni]);
                }
            }
        }
        LGKM0();                                        // no ds_read outstanding
        RBARRIER();                                     // all waves done reading cur
        if (t + 2 < NT) STAGE(cur);                     // reuse cur for tile t+2
    }
    // after final barrier all waves are done reading smem -> reuse for epilogue

    // acc D layout: col = lane&15, row = (lane>>4)*4 + reg
    const int bidx  = m0 >> 12;
    const int rbl   = wr * (TM / 2) + (lane >> 4) * 4;   // local row base
    const int cbl   = wc * CW + (lane & 15);             // local col base

    if constexpr (EPI == 0) {
        // bf16 output tile [TM][BN+8], + f32 colsum atomics from registers
        constexpr int BNP = BN + 8;
        unsigned short* tile = &smem[0][0];
        float csum[NI];
#pragma unroll
        for (int ni = 0; ni < NI; ni++) csum[ni] = 0.f;
#pragma unroll
        for (int ni = 0; ni < NI; ni++) {
            float bb = mb[n0 + cbl + ni * 16];
#pragma unroll
            for (int mi = 0; mi < MI; mi++) {
#pragma unroll
                for (int r = 0; r < 4; r++) {
                    float val = acc[0][mi][ni][r] + bb;
                    tile[(rbl + mi * 16 + r) * BNP + cbl + ni * 16] = f2bf(val);
                    csum[ni] += val;
                }
            }
        }
        __syncthreads();
        constexpr int QR = BN / 8;                       // int4 chunks per row
        for (int idx = tid; idx < TM * QR; idx += NTHR) {
            int row = idx / QR, q = idx % QR;
            int4 v = *(const int4*)&tile[row * BNP + q * 8];
            *(int4*)(outB0 + (size_t)(m0 + row) * HDIM + n0 + q * 8) = v;
        }
#pragma unroll
        for (int ni = 0; ni < NI; ni++) {
            float sc = csum[ni];
            sc += __shfl_xor(sc, 16, 64);
            sc += __shfl_xor(sc, 32, 64);
            if (lane < 16)
                atomicAdd(&msum_out[bidx * HDIM + n0 + wc * CW + ni * 16 + lane], sc);
        }
    } else if constexpr (EPI == 1) {
        constexpr int BNP = BN + 8;
        unsigned short* tS = &smem[0][0];
        unsigned short* tR = &smem[0][0] + TM * BNP;
#pragma unroll
        for (int ni = 0; ni < NI; ni++) {
            int gcol = n0 + cbl + ni * 16;
            float mk = mb[(0 * BDIM + bidx) * HDIM + gcol];
            float mv = mb[(1 * BDIM + bidx) * HDIM + gcol];
            float mr = mb[(2 * BDIM + bidx) * HDIM + gcol];
#pragma unroll
            for (int mi = 0; mi < MI; mi++) {
#pragma unroll
                for (int r = 0; r < 4; r++) {
                    float kk_ = fmaxf(acc[0][mi][ni][r] + mk, 0.f);
                    float vv  = fmaxf(acc[NMAT > 1 ? 1 : 0][mi][ni][r] + mv, 0.f);
                    float rr  = fast_rcp(1.f + __expf(-(acc[NMAT > 2 ? 2 : 0][mi][ni][r] + mr)));
                    float sv  = vv * fast_rcp(1.f + __expf(-kk_));
                    int loc = (rbl + mi * 16 + r) * BNP + cbl + ni * 16;
                    tS[loc] = f2bf(sv);
                    tR[loc] = f2bf(rr);
                }
            }
        }
        __syncthreads();
        constexpr int QR = BN / 8;
        for (int idx = tid; idx < 2 * TM * QR; idx += NTHR) {
            int tn = idx / (TM * QR), rem = idx % (TM * QR);
            int row = rem / QR, q = rem % QR;
            int4 v = *(const int4*)&smem[0][tn * TM * BNP + row * BNP + q * 8];
            unsigned short* dst = tn ? outB1 : outB0;
            *(int4*)(dst + (size_t)(m0 + row) * HDIM + n0 + q * 8) = v;
        }
    } else {
        // plain bf16 output tile
        constexpr int BNP = BN + 8;
        unsigned short* tile = &smem[0][0];
#pragma unroll
        for (int ni = 0; ni < NI; ni++) {
#pragma unroll
            for (int mi = 0; mi < MI; mi++) {
#pragma unroll
                for (int r = 0; r < 4; r++)
                    tile[(rbl + mi * 16 + r) * BNP + cbl + ni * 16] = f2bf(acc[0][mi][ni][r]);
            }
        }
        __syncthreads();
        constexpr int QR = BN / 8;
        for (int idx = tid; idx < TM * QR; idx += NTHR) {
            int row = idx / QR, q = idx % QR;
            int4 v = *(const int4*)&tile[row * BNP + q * 8];
            *(int4*)(outB0 + (size_t)(m0 + row) * HDIM + n0 + q * 8) = v;
        }
    }
}

// ---------------------------------------------------------------------------
// wkv scan, chunked C=64 with 64-step halo (0.9^64 ~ 1.2e-3 < bf16 quantum).
// y = bf16(r*wkv). 512 blocks x 4 waves = 2 waves/SIMD.
// ---------------------------------------------------------------------------
__global__ void scan_k(const unsigned short* __restrict__ s_bf,
                       const unsigned short* __restrict__ r_bf,
                       unsigned short* __restrict__ y_bf)
{
    const int C = 64, W = 64;
    const int b  = blockIdx.z;
    const int t0 = blockIdx.x * C;
    const int h2 = threadIdx.x * 2;
    const size_t rowbase = (size_t)b * S_LEN;

    float a0 = 0.f, a1 = 0.f;
    int tstart = t0 - W; if (tstart < 0) tstart = 0;
#pragma unroll 4
    for (int t = tstart; t < t0; t++) {
        unsigned u = *(const unsigned*)(s_bf + (rowbase + t) * HDIM + h2);
        a0 = bf2f((unsigned short)(u & 0xffff)) + 0.9f * a0;
        a1 = bf2f((unsigned short)(u >> 16))    + 0.9f * a1;
    }
#pragma unroll 4
    for (int t = t0; t < t0 + C; t++) {
        size_t off = (rowbase + t) * HDIM + h2;
        unsigned u  = *(const unsigned*)(s_bf + off);
        unsigned ur = *(const unsigned*)(r_bf + off);
        float s0 = bf2f((unsigned short)(u & 0xffff));
        float s1 = bf2f((unsigned short)(u >> 16));
        float w0 = s0 + a0, w1v = s1 + a1;
        a0 = s0 + 0.9f * a0;
        a1 = s1 + 0.9f * a1;
        float r0 = bf2f((unsigned short)(ur & 0xffff));
        float r1 = bf2f((unsigned short)(ur >> 16));
        unsigned outp = (unsigned)f2bf(r0 * w0) | ((unsigned)f2bf(r1 * w1v) << 16);
        *(unsigned*)(y_bf + off) = outp;
    }
}

// ---------------------------------------------------------------------------
// Fused: out = LN(h+o); ff = relu(LN(out)); hnew = out+ff.
// h and O are bf16. Writes f32 (dstF) and/or bf16 (dst_bf); optional
// per-(b,col) colsum atomics for the next layer's sequence mean.
// Grid (128, B): 1024 blocks = 4 waves/SIMD.
// ---------------------------------------------------------------------------
__global__ __launch_bounds__(256) void lnfuse_k(
    const unsigned short* __restrict__ Hb, const unsigned short* __restrict__ O,
    const float* __restrict__ w1, const float* __restrict__ b1,
    const float* __restrict__ w2, const float* __restrict__ b2,
    float* __restrict__ dstF, unsigned short* __restrict__ dst_bf,
    float* __restrict__ msum_next)
{
    __shared__ float red[HDIM];
    const int b    = blockIdx.y;
    const int tid  = threadIdx.x;
    const int wid  = tid >> 6, lane = tid & 63;
    const int wglob = blockIdx.x * 4 + wid;              // 0..511
    const int c0   = lane * 8;

    float w1v[8], b1v[8], w2v[8], b2v[8];
#pragma unroll
    for (int j = 0; j < 8; j++) {
        w1v[j] = w1[c0 + j]; b1v[j] = b1[c0 + j];
        w2v[j] = w2[c0 + j]; b2v[j] = b2[c0 + j];
    }
    float macc[8] = {0.f, 0.f, 0.f, 0.f, 0.f, 0.f, 0.f, 0.f};

    for (int s = wglob; s < S_LEN; s += 512) {
        size_t ro = ((size_t)b * S_LEN + s) * HDIM + c0;
        int4 hv4 = *(const int4*)(Hb + ro);
        int4 ov4 = *(const int4*)(O + ro);
        const unsigned short* hu = (const unsigned short*)&hv4;
        const unsigned short* ou = (const unsigned short*)&ov4;
        float x[8];
#pragma unroll
        for (int j = 0; j < 8; j++) x[j] = bf2f(hu[j]) + bf2f(ou[j]);
        float sm = 0.f;
#pragma unroll
        for (int j = 0; j < 8; j++) sm += x[j];
        float mu = wave_sum(sm) * (1.f / HDIM);
        float sq = 0.f;
#pragma unroll
        for (int j = 0; j < 8; j++) { float d = x[j] - mu; sq += d * d; }
        float rs = fast_rsq(wave_sum(sq) * (1.f / HDIM) + 1e-5f);
        float out[8];
#pragma unroll
        for (int j = 0; j < 8; j++) out[j] = (x[j] - mu) * rs * w1v[j] + b1v[j];
        float sm2 = 0.f;
#pragma unroll
        for (int j = 0; j < 8; j++) sm2 += out[j];
        float mu2 = wave_sum(sm2) * (1.f / HDIM);
        float sq2 = 0.f;
#pragma unroll
        for (int j = 0; j < 8; j++) { float d = out[j] - mu2; sq2 += d * d; }
        float rs2 = fast_rsq(wave_sum(sq2) * (1.f / HDIM) + 1e-5f);
        float hn[8];
#pragma unroll
        for (int j = 0; j < 8; j++) {
            float ff = fmaxf(0.f, (out[j] - mu2) * rs2 * w2v[j] + b2v[j]);
            hn[j] = out[j] + ff;
            macc[j] += hn[j];
        }
        if (dstF) {
            float4 o1 = {hn[0], hn[1], hn[2], hn[3]};
            float4 o2 = {hn[4], hn[5], hn[6], hn[7]};
            *(float4*)(dstF + ro) = o1;
            *(float4*)(dstF + ro + 4) = o2;
        }
        if (dst_bf) {
            unsigned q[4];
#pragma unroll
            for (int j = 0; j < 4; j++)
                q[j] = (unsigned)f2bf(hn[2 * j]) | ((unsigned)f2bf(hn[2 * j + 1]) << 16);
            *(int4*)(dst_bf + ro) = *(int4*)q;
        }
    }

    if (msum_next) {
        for (int i = tid; i < HDIM; i += 256) red[i] = 0.f;
        __syncthreads();
#pragma unroll
        for (int j = 0; j < 8; j++) atomicAdd(&red[c0 + j], macc[j]);
        __syncthreads();
        for (int i = tid; i < HDIM; i += 256)
            atomicAdd(&msum_next[b * HDIM + i], red[i]);
    }
}

// ---------------------------------------------------------------------------
extern "C" void kernel_launch(void* const* d_in, const int* in_sizes, int n_in,
                              void* d_out, int out_size, void* d_ws, size_t ws_size,
                              hipStream_t stream)
{
    const float* x   = (const float*)d_in[0];
    const float* Win = (const float*)d_in[1];
    const float* bin = (const float*)d_in[2];
    const float* tmk = (const float*)d_in[3];
    const float* tmv = (const float*)d_in[4];
    const float* tmr = (const float*)d_in[5];
    const float* Wk  = (const float*)d_in[6];
    const float* Wv  = (const float*)d_in[7];
    const float* Wr  = (const float*)d_in[8];
    const float* Wo  = (const float*)d_in[9];
    const float* l1w = (const float*)d_in[10];
    const float* l1b = (const float*)d_in[11];
    const float* l2w = (const float*)d_in[12];
    const float* l2b = (const float*)d_in[13];

    char* ws = (char*)d_ws;
    size_t off = 0;
    auto alloc = [&](size_t bytes) -> char* {
        char* p = ws + off;
        off += (bytes + 255) & ~(size_t)255;
        return p;
    };
    const size_t NTOK = (size_t)BDIM * S_LEN;            // 32768 rows
    const size_t HH = (size_t)HDIM * HDIM;
    // region0: x_bf during input proj, then reused as y_bf
    unsigned short* region0 = (unsigned short*)alloc(NTOK * HDIM * 2);
    unsigned short* x_bf   = region0;
    unsigned short* y_bf   = region0;
    unsigned short* Win_bf = (unsigned short*)alloc((size_t)HDIM * DIN * 2);
    unsigned short* Wo_bf  = (unsigned short*)alloc(NLAYER * HH * 2);
    unsigned short* Wf     = (unsigned short*)alloc(NLAYER * 3 * HH * 2);
    unsigned short* h_bf   = (unsigned short*)alloc(NTOK * HDIM * 2);   // layer-0 h
    unsigned short* h2_bf  = (unsigned short*)alloc(NTOK * HDIM * 2);   // layer-1 h
    unsigned short* s_bf   = (unsigned short*)alloc(NTOK * HDIM * 2);
    unsigned short* r_bf   = (unsigned short*)alloc(NTOK * HDIM * 2);
    unsigned short* o_bf   = (unsigned short*)alloc(NTOK * HDIM * 2);   // Wo out (bf16)
    float*          msum   = (float*)alloc(2 * BDIM * HDIM * 4);
    float*          mbuf   = (float*)alloc(3 * BDIM * HDIM * 4);

    hipMemsetAsync(msum, 0, 2 * BDIM * HDIM * 4, stream);

    // merged f32->bf16 conversions: x, Win, Wo in one launch
    {
        int na4 = (int)(NTOK * DIN / 4);
        int nb4 = (int)((size_t)HDIM * DIN / 4);
        int nc4 = (int)(NLAYER * HH / 4);
        int tot = na4 + nb4 + nc4;
        cvt3_k<<<(tot + 255) / 256, 256, 0, stream>>>(
            x, x_bf, na4, Win, Win_bf, nb4, Wo, Wo_bf, nc4);
    }
    {
        int n4 = NLAYER * 3 * HH / 4;
        cvtw_k<<<(n4 + 255) / 256, 256, 0, stream>>>(Wk, Wv, Wr, tmk, tmv, tmr, Wf);
    }

    const float invS = 1.f / S_LEN;

    // h = bf16(x @ W_in^T + b_in)  (+ colsums into msum[0]); NW=8
    gemm2_k<128, 128, 1, 0, DIN, 4, 8><<<1024, 512, 0, stream>>>(
        x_bf, Win_bf, nullptr, nullptr, bin, h_bf, nullptr, msum);

    for (int l = 0; l < NLAYER; l++) {
        const unsigned short* hl = (l == 0) ? h_bf : h2_bf;
        // per-batch mean-bias vectors for k,v,r
        meanbias_k<<<dim3(3, BDIM, 8), 256, 0, stream>>>(
            msum + (size_t)l * BDIM * HDIM, invS,
            Wk + (size_t)l * HH, Wv + (size_t)l * HH, Wr + (size_t)l * HH,
            tmk + l * HDIM, tmv + l * HDIM, tmr + l * HDIM, mbuf);
        // fused k/v/r GEMM (folded weights): s_bf, r_bf — NW=8 (512 threads),
        // 2 blocks/CU, 4 waves/SIMD at the same dbuf counted-vmcnt schedule
        gemm2_k<128, 64, 3, 1, HDIM, 8, 8><<<2048, 512, 0, stream>>>(
            hl,
            Wf + ((size_t)l * 3 + 0) * HH, Wf + ((size_t)l * 3 + 1) * HH,
            Wf + ((size_t)l * 3 + 2) * HH,
            mbuf, s_bf, r_bf, nullptr);
        // wkv scan + y = r*wkv
        scan_k<<<dim3(S_LEN / 64, 1, BDIM), 256, 0, stream>>>(s_bf, r_bf, y_bf);
        // out_pre = bf16(y @ Wo^T), coalesced; NW=8
        gemm2_k<128, 128, 1, 3, HDIM, 4, 8><<<1024, 512, 0, stream>>>(
            y_bf, Wo_bf + (size_t)l * HH, nullptr, nullptr,
            nullptr, o_bf, nullptr, nullptr);
        // LN1 + LN2 + relu + residuals
        lnfuse_k<<<dim3(128, BDIM), 256, 0, stream>>>(
            hl, o_bf, l1w + l * HDIM, l1b + l * HDIM, l2w + l * HDIM, l2b + l * HDIM,
            (l == 0) ? nullptr : (float*)d_out,
            (l == 0) ? h2_bf : nullptr,
            (l == 0) ? (msum + BDIM * HDIM) : nullptr);
    }
}

// Round 12
// 315.662 us; speedup vs baseline: 1.0363x; 1.0363x over previous
//
#include <hip/hip_runtime.h>
#include <hip/hip_bf16.h>
#include <cstdint>
#include <cstddef>

#define S_LEN 4096
#define HDIM  512
#define BDIM  8
#define DIN   256
#define NLAYER 2

using float4v = __attribute__((ext_vector_type(4))) float;
using short8  = __attribute__((ext_vector_type(8))) short;
using bf16x8  = __attribute__((ext_vector_type(8))) __bf16;

struct __align__(8) us4_t { unsigned short x, y, z, w; };

// native bf16 cast: single v_cvt_pk_bf16_f32 (RNE), compiler-selected.
__device__ __forceinline__ unsigned short f2bf(float f) {
    return __builtin_bit_cast(unsigned short, (__bf16)f);
}
__device__ __forceinline__ float bf2f(unsigned short s) {
    union { unsigned u; float f; } v; v.u = ((unsigned)s) << 16;
    return v.f;
}
// hardware-approx rcp/rsq (~1 ulp): outputs are bf16-rounded downstream, and
// inputs are bounded away from the edge cases (rcp arg >= 1, rsq arg >= 1e-5).
__device__ __forceinline__ float fast_rcp(float x) { return __builtin_amdgcn_rcpf(x); }
__device__ __forceinline__ float fast_rsq(float x) { return __builtin_amdgcn_rsqf(x); }

// 16x16x32: 16 rows/fragment-read -> free 2-way LDS aliasing with the 8-slot
// XOR swizzle. (R4: 32x32x16 pigeonholes 4 rows/slot -> 5.5M conflicts.
// R8: single-buffer 4-block occupancy loses to dbuf counted-vmcnt 2-block.
// R10/R11: NW=8 helps ONLY the NMAT=3 kvr GEMM (+10%) — its 3 B-mats
// amortize the per-wave fragment-read amplification and its stage drains
// are longest. NMAT=1 GEMMs regress at NW=8 (1.5x LDS reads, 8 MFMA per
// 6 reads): keep them at NW=4. Wave count is coupled to compute density.)
__device__ __forceinline__ float4v mfma_bf16(short8 a, short8 b, float4v c) {
    return __builtin_amdgcn_mfma_f32_16x16x32_bf16(
        __builtin_bit_cast(bf16x8, a), __builtin_bit_cast(bf16x8, b), c, 0, 0, 0);
}
__device__ __forceinline__ float wave_sum(float v) {
#pragma unroll
    for (int m = 1; m < 64; m <<= 1) v += __shfl_xor(v, m, 64);
    return v;
}
// async global->LDS, 16B per lane. LDS dest is wave-uniform base + lane*16.
__device__ __forceinline__ void gload16(const void* g, void* l) {
    __builtin_amdgcn_global_load_lds(
        (const __attribute__((address_space(1))) unsigned int*)g,
        (__attribute__((address_space(3))) unsigned int*)l,
        16, 0, 0);
}

// counted vmcnt wait + raw barrier (T4: never drain to 0 in steady state)
#define VMW_ASM(N) asm volatile("s_waitcnt vmcnt(" #N ")" ::: "memory")
template<int N> __device__ __forceinline__ void vmwait() {
    static_assert(N == 0 || N == 4 || N == 5 || N == 6 || N == 8 || N == 10,
                  "add a case for this N");
    if constexpr (N == 0) VMW_ASM(0);
    else if constexpr (N == 4) VMW_ASM(4);
    else if constexpr (N == 5) VMW_ASM(5);
    else if constexpr (N == 6) VMW_ASM(6);
    else if constexpr (N == 8) VMW_ASM(8);
    else if constexpr (N == 10) VMW_ASM(10);
}
#define LGKM0()    asm volatile("s_waitcnt lgkmcnt(0)" ::: "memory")
#define RBARRIER() asm volatile("s_barrier" ::: "memory")

// merged head conversions in ONE launch:
//   seg 0: x  f32->bf16       seg 1: Win f32->bf16      seg 2: Wo f32->bf16
//   seg 3: Wf[l][j][o][k] = bf16( W_j[l][o][k] * t_j[l][k] ), j in {k,v,r}
__global__ void cvt4_k(const float* __restrict__ a, unsigned short* __restrict__ oa, int na4,
                       const float* __restrict__ b, unsigned short* __restrict__ ob, int nb4,
                       const float* __restrict__ c, unsigned short* __restrict__ oc2, int nc4,
                       const float* __restrict__ Wk, const float* __restrict__ Wv,
                       const float* __restrict__ Wr,
                       const float* __restrict__ tmk, const float* __restrict__ tmv,
                       const float* __restrict__ tmr,
                       unsigned short* __restrict__ Wf, int nf4)
{
    int i = blockIdx.x * blockDim.x + threadIdx.x;
    if (i < na4 + nb4 + nc4) {
        const float* src; unsigned short* dst; int idx;
        if (i < na4)            { src = a; dst = oa;  idx = i; }
        else if (i < na4 + nb4) { src = b; dst = ob;  idx = i - na4; }
        else                    { src = c; dst = oc2; idx = i - na4 - nb4; }
        float4 v = ((const float4*)src)[idx];
        us4_t o;
        o.x = f2bf(v.x); o.y = f2bf(v.y); o.z = f2bf(v.z); o.w = f2bf(v.w);
        ((us4_t*)dst)[idx] = o;
        return;
    }
    int fi = i - (na4 + nb4 + nc4);
    if (fi >= nf4) return;
    int e = fi * 4;
    const int HH = HDIM * HDIM;
    int l   = (e >= 3 * HH) ? 1 : 0;
    int rem = e - l * 3 * HH;
    int j   = rem >> 18;                                  // / (512*512)
    int ok  = rem & (HH - 1);
    int k   = ok & (HDIM - 1);
    const float* W = (j == 0) ? Wk : (j == 1) ? Wv : Wr;
    const float* t = (j == 0) ? tmk : (j == 1) ? tmv : tmr;
    float4 w = *(const float4*)(W + (size_t)l * HH + ok);
    const float* tp = t + l * HDIM + k;
    us4_t o;
    o.x = f2bf(w.x * tp[0]); o.y = f2bf(w.y * tp[1]);
    o.z = f2bf(w.z * tp[2]); o.w = f2bf(w.w * tp[3]);
    *(us4_t*)(Wf + e) = o;
}

// mb[j][b][o] = sum_k (1 - t_j[k]) * mean[b,k] * W_j[o,k]   (f32 weights)
__global__ void meanbias_k(const float* __restrict__ msum_l, float invS,
    const float* __restrict__ Wk, const float* __restrict__ Wv, const float* __restrict__ Wr,
    const float* __restrict__ tmk, const float* __restrict__ tmv, const float* __restrict__ tmr,
    float* __restrict__ mb)
{
    __shared__ float m2[HDIM];
    const int j = blockIdx.x, b = blockIdx.y, oc = blockIdx.z;  // (3, 8, 8)
    const int tid = threadIdx.x, lane = tid & 63, wid = tid >> 6;
    const float* W = (j == 0) ? Wk : (j == 1) ? Wv : Wr;
    const float* t = (j == 0) ? tmk : (j == 1) ? tmv : tmr;
    for (int i = tid; i < HDIM; i += 256)
        m2[i] = msum_l[b * HDIM + i] * invS * (1.f - t[i]);
    __syncthreads();
    const int o0 = oc * 64 + wid * 16;
    for (int oo = 0; oo < 16; oo++) {
        int o = o0 + oo;
        const float* wr_ = W + (size_t)o * HDIM + lane * 8;
        float4 w0 = *(const float4*)wr_;
        float4 w1 = *(const float4*)(wr_ + 4);
        const float* mp = m2 + lane * 8;
        float s = w0.x * mp[0] + w0.y * mp[1] + w0.z * mp[2] + w0.w * mp[3]
                + w1.x * mp[4] + w1.y * mp[5] + w1.z * mp[6] + w1.w * mp[7];
        s = wave_sum(s);
        if (lane == 0) mb[((size_t)j * BDIM + b) * HDIM + o] = s;
    }
}

// ---------------------------------------------------------------------------
// bf16 MFMA GEMM: out_j[m,o] = sum_k A[m,k] * B_j[o,k], all operands bf16.
// Staging: global_load_lds width-16, double-buffered LDS, XOR-swizzled
// (source pre-swizzle + swizzled read, linear LDS dest).
// Counted-vmcnt pipeline: raw s_barrier + s_waitcnt vmcnt(NCW) — exactly the
// own-tile loads retire; the next tile's NCW loads stay in flight.
// 2 blocks/CU; 1D grid, XCD-chunked mapping, col-fastest logical order.
// NW: 8 for kvr (NMAT=3, latency-bound, 3 B-mats amortize frag reads);
//     4 for NMAT=1 GEMMs (NW=8 regressed them — R11).
// Wave (wr, wc) grid: 2 x (NW/2); per-wave tile TM/2 x BN/(NW/2) per mat.
// Epilogues stage the output tile in LDS and write fully-coalesced dwordx4.
// EPI 1 sigmoids use v_rcp_f32; f32->bf16 via native cast (v_cvt_pk_bf16_f32).
// EPI 0: +bias -> bf16 out + per-(b,col) colsum atomics (input proj)
// EPI 1: kvr fused: s = relu(v+mbv)*sigmoid(relu(k+mbk)); r = sigmoid(.+mbr)
// EPI 3: plain bf16 out (Wo proj)
// ---------------------------------------------------------------------------
template<int TM, int BN, int NMAT, int EPI, int K, int NY, int NW>
__global__ __launch_bounds__(NW * 64, 2) void gemm2_k(
    const unsigned short* __restrict__ A,
    const unsigned short* __restrict__ B0,
    const unsigned short* __restrict__ B1,
    const unsigned short* __restrict__ B2,
    const float* __restrict__ mb,          // EPI=0: bias[512]; EPI=1: [3][8][512]
    unsigned short* __restrict__ outB0,
    unsigned short* __restrict__ outB1,
    float* __restrict__ msum_out)
{
    constexpr int NTHR = NW * 64;
    constexpr int NT   = K / 64;
    static_assert(NT >= 2, "pipeline needs >=2 K-tiles");
    constexpr int ROWS = TM + NMAT * BN;    // 128B rows per buffer
    constexpr int NC   = ROWS / 8;          // 1KB chunks
    static_assert(NC % NW == 0, "chunks must split evenly across waves");
    constexpr int NCW  = NC / NW;           // chunks per wave (= loads in flight/stage)
    constexpr int WC   = NW / 2;            // waves along cols
    constexpr int MI   = TM / 32;           // row frags per wave (TM/2 rows)
    constexpr int CW   = BN / WC;           // cols per wave per mat
    constexpr int NI   = CW / 16;           // col frags per wave per mat
    static_assert(NI >= 1, "");
    __shared__ __align__(16) unsigned short smem[2][ROWS * 64];
    static_assert((EPI == 1 ? 2 : 1) * TM * (BN + 8) <= 2 * ROWS * 64,
                  "epilogue overflow");

    const int tid = threadIdx.x, lane = tid & 63, wid = tid >> 6;
    const int wr = wid / WC, wc = wid % WC;
    // XCD-chunked bijective remap (gridDim.x % 8 == 0), col-fastest logical
    const int chunk = gridDim.x >> 3;
    const int logical = (blockIdx.x & 7) * chunk + (blockIdx.x >> 3);
    const int m0 = (logical / NY) * TM, n0 = (logical % NY) * BN;

    // per-chunk global pointers (source pre-swizzled: slot' = (lane&7) ^ (lane>>3))
    const int l8 = lane >> 3;
    const int soff = (((lane & 7) ^ l8) * 16);
    const char* gp[NCW];
#pragma unroll
    for (int i = 0; i < NCW; i++) {
        int c = wid * NCW + i;
        const unsigned short* base; int row;
        if (c < TM / 8) { base = A; row = m0 + c * 8 + l8; }
        else {
            int cb = c - TM / 8;
            int j  = cb / (BN / 8);
            int rl = (cb % (BN / 8)) * 8 + l8;
            base = (j == 0) ? B0 : ((j == 1) ? B1 : B2);
            row  = n0 + rl;
        }
        gp[i] = (const char*)base + (size_t)row * (K * 2) + soff;
    }

    float4v acc[NMAT][MI][NI];
#pragma unroll
    for (int j = 0; j < NMAT; j++)
#pragma unroll
        for (int mi = 0; mi < MI; mi++)
#pragma unroll
            for (int ni = 0; ni < NI; ni++)
                acc[j][mi][ni] = (float4v){0.f, 0.f, 0.f, 0.f};

    auto STAGE = [&](int buf) {
#pragma unroll
        for (int i = 0; i < NCW; i++) {
            gload16(gp[i], (char*)&smem[buf][0] + (unsigned)(wid * NCW + i) * 1024);
            gp[i] += 128;                               // advance one K-step (64 bf16)
        }
    };

    STAGE(0);                                           // tile 0 -> buf0
    STAGE(1);                                           // tile 1 -> buf1
    for (int t = 0; t < NT; t++) {
        // own stage(t) loads retired (in-order); stage(t+1) stays in flight
        if (t == NT - 1) vmwait<0>(); else vmwait<NCW>();
        RBARRIER();                                     // all waves: tile t landed
        const int cur = t & 1;
        const unsigned short* As = &smem[cur][0];
        const unsigned short* Bs = &smem[cur][TM * 64];
#pragma unroll
        for (int kk = 0; kk < 2; kk++) {
            short8 a_[MI];
#pragma unroll
            for (int mi = 0; mi < MI; mi++) {
                int row = wr * (TM / 2) + mi * 16 + (lane & 15);
                int sl  = (kk * 4 + (lane >> 4)) ^ (row & 7);
                a_[mi] = *(const short8*)&As[row * 64 + sl * 8];
            }
#pragma unroll
            for (int ni = 0; ni < NI; ni++) {
                int rowb = wc * CW + ni * 16 + (lane & 15);
                int slb  = (kk * 4 + (lane >> 4)) ^ (rowb & 7);
#pragma unroll
                for (int j = 0; j < NMAT; j++) {
                    short8 b_ = *(const short8*)&Bs[(j * BN + rowb) * 64 + slb * 8];
#pragma unroll
                    for (int mi = 0; mi < MI; mi++)
                        acc[j][mi][ni] = mfma_bf16(a_[mi], b_, acc[j][mi][ni]);
                }
            }
        }
        LGKM0();                                        // no ds_read outstanding
        RBARRIER();                                     // all waves done reading cur
        if (t + 2 < NT) STAGE(cur);                     // reuse cur for tile t+2
    }
    // after final barrier all waves are done reading smem -> reuse for epilogue

    // acc D layout: col = lane&15, row = (lane>>4)*4 + reg
    const int bidx  = m0 >> 12;
    const int rbl   = wr * (TM / 2) + (lane >> 4) * 4;   // local row base
    const int cbl   = wc * CW + (lane & 15);             // local col base

    if constexpr (EPI == 0) {
        // bf16 output tile [TM][BN+8], + f32 colsum atomics from registers
        constexpr int BNP = BN + 8;
        unsigned short* tile = &smem[0][0];
        float csum[NI];
#pragma unroll
        for (int ni = 0; ni < NI; ni++) csum[ni] = 0.f;
#pragma unroll
        for (int ni = 0; ni < NI; ni++) {
            float bb = mb[n0 + cbl + ni * 16];
#pragma unroll
            for (int mi = 0; mi < MI; mi++) {
#pragma unroll
                for (int r = 0; r < 4; r++) {
                    float val = acc[0][mi][ni][r] + bb;
                    tile[(rbl + mi * 16 + r) * BNP + cbl + ni * 16] = f2bf(val);
                    csum[ni] += val;
                }
            }
        }
        __syncthreads();
        constexpr int QR = BN / 8;                       // int4 chunks per row
        for (int idx = tid; idx < TM * QR; idx += NTHR) {
            int row = idx / QR, q = idx % QR;
            int4 v = *(const int4*)&tile[row * BNP + q * 8];
            *(int4*)(outB0 + (size_t)(m0 + row) * HDIM + n0 + q * 8) = v;
        }
#pragma unroll
        for (int ni = 0; ni < NI; ni++) {
            float sc = csum[ni];
            sc += __shfl_xor(sc, 16, 64);
            sc += __shfl_xor(sc, 32, 64);
            if (lane < 16)
                atomicAdd(&msum_out[bidx * HDIM + n0 + wc * CW + ni * 16 + lane], sc);
        }
    } else if constexpr (EPI == 1) {
        constexpr int BNP = BN + 8;
        unsigned short* tS = &smem[0][0];
        unsigned short* tR = &smem[0][0] + TM * BNP;
#pragma unroll
        for (int ni = 0; ni < NI; ni++) {
            int gcol = n0 + cbl + ni * 16;
            float mk = mb[(0 * BDIM + bidx) * HDIM + gcol];
            float mv = mb[(1 * BDIM + bidx) * HDIM + gcol];
            float mr = mb[(2 * BDIM + bidx) * HDIM + gcol];
#pragma unroll
            for (int mi = 0; mi < MI; mi++) {
#pragma unroll
                for (int r = 0; r < 4; r++) {
                    float kk_ = fmaxf(acc[0][mi][ni][r] + mk, 0.f);
                    float vv  = fmaxf(acc[NMAT > 1 ? 1 : 0][mi][ni][r] + mv, 0.f);
                    float rr  = fast_rcp(1.f + __expf(-(acc[NMAT > 2 ? 2 : 0][mi][ni][r] + mr)));
                    float sv  = vv * fast_rcp(1.f + __expf(-kk_));
                    int loc = (rbl + mi * 16 + r) * BNP + cbl + ni * 16;
                    tS[loc] = f2bf(sv);
                    tR[loc] = f2bf(rr);
                }
            }
        }
        __syncthreads();
        constexpr int QR = BN / 8;
        for (int idx = tid; idx < 2 * TM * QR; idx += NTHR) {
            int tn = idx / (TM * QR), rem = idx % (TM * QR);
            int row = rem / QR, q = rem % QR;
            int4 v = *(const int4*)&smem[0][tn * TM * BNP + row * BNP + q * 8];
            unsigned short* dst = tn ? outB1 : outB0;
            *(int4*)(dst + (size_t)(m0 + row) * HDIM + n0 + q * 8) = v;
        }
    } else {
        // plain bf16 output tile
        constexpr int BNP = BN + 8;
        unsigned short* tile = &smem[0][0];
#pragma unroll
        for (int ni = 0; ni < NI; ni++) {
#pragma unroll
            for (int mi = 0; mi < MI; mi++) {
#pragma unroll
                for (int r = 0; r < 4; r++)
                    tile[(rbl + mi * 16 + r) * BNP + cbl + ni * 16] = f2bf(acc[0][mi][ni][r]);
            }
        }
        __syncthreads();
        constexpr int QR = BN / 8;
        for (int idx = tid; idx < TM * QR; idx += NTHR) {
            int row = idx / QR, q = idx % QR;
            int4 v = *(const int4*)&tile[row * BNP + q * 8];
            *(int4*)(outB0 + (size_t)(m0 + row) * HDIM + n0 + q * 8) = v;
        }
    }
}

// ---------------------------------------------------------------------------
// wkv scan, chunked C=64 with 64-step halo (0.9^64 ~ 1.2e-3 < bf16 quantum).
// y = bf16(r*wkv). 512 blocks x 4 waves = 2 waves/SIMD. Runs at ~6.3 TB/s
// effective (R5 traffic-delta arithmetic) — BW floor; do not add halo traffic.
// ---------------------------------------------------------------------------
__global__ void scan_k(const unsigned short* __restrict__ s_bf,
                       const unsigned short* __restrict__ r_bf,
                       unsigned short* __restrict__ y_bf)
{
    const int C = 64, W = 64;
    const int b  = blockIdx.z;
    const int t0 = blockIdx.x * C;
    const int h2 = threadIdx.x * 2;
    const size_t rowbase = (size_t)b * S_LEN;

    float a0 = 0.f, a1 = 0.f;
    int tstart = t0 - W; if (tstart < 0) tstart = 0;
#pragma unroll 4
    for (int t = tstart; t < t0; t++) {
        unsigned u = *(const unsigned*)(s_bf + (rowbase + t) * HDIM + h2);
        a0 = bf2f((unsigned short)(u & 0xffff)) + 0.9f * a0;
        a1 = bf2f((unsigned short)(u >> 16))    + 0.9f * a1;
    }
#pragma unroll 4
    for (int t = t0; t < t0 + C; t++) {
        size_t off = (rowbase + t) * HDIM + h2;
        unsigned u  = *(const unsigned*)(s_bf + off);
        unsigned ur = *(const unsigned*)(r_bf + off);
        float s0 = bf2f((unsigned short)(u & 0xffff));
        float s1 = bf2f((unsigned short)(u >> 16));
        float w0 = s0 + a0, w1v = s1 + a1;
        a0 = s0 + 0.9f * a0;
        a1 = s1 + 0.9f * a1;
        float r0 = bf2f((unsigned short)(ur & 0xffff));
        float r1 = bf2f((unsigned short)(ur >> 16));
        unsigned outp = (unsigned)f2bf(r0 * w0) | ((unsigned)f2bf(r1 * w1v) << 16);
        *(unsigned*)(y_bf + off) = outp;
    }
}

// ---------------------------------------------------------------------------
// Fused: out = LN(h+o); ff = relu(LN(out)); hnew = out+ff.
// h and O are bf16. Writes f32 (dstF) and/or bf16 (dst_bf); optional
// per-(b,col) colsum atomics for the next layer's sequence mean.
// Grid (128, B): 1024 blocks = 4 waves/SIMD.
// ---------------------------------------------------------------------------
__global__ __launch_bounds__(256) void lnfuse_k(
    const unsigned short* __restrict__ Hb, const unsigned short* __restrict__ O,
    const float* __restrict__ w1, const float* __restrict__ b1,
    const float* __restrict__ w2, const float* __restrict__ b2,
    float* __restrict__ dstF, unsigned short* __restrict__ dst_bf,
    float* __restrict__ msum_next)
{
    __shared__ float red[HDIM];
    const int b    = blockIdx.y;
    const int tid  = threadIdx.x;
    const int wid  = tid >> 6, lane = tid & 63;
    const int wglob = blockIdx.x * 4 + wid;              // 0..511
    const int c0   = lane * 8;

    float w1v[8], b1v[8], w2v[8], b2v[8];
#pragma unroll
    for (int j = 0; j < 8; j++) {
        w1v[j] = w1[c0 + j]; b1v[j] = b1[c0 + j];
        w2v[j] = w2[c0 + j]; b2v[j] = b2[c0 + j];
    }
    float macc[8] = {0.f, 0.f, 0.f, 0.f, 0.f, 0.f, 0.f, 0.f};

    for (int s = wglob; s < S_LEN; s += 512) {
        size_t ro = ((size_t)b * S_LEN + s) * HDIM + c0;
        int4 hv4 = *(const int4*)(Hb + ro);
        int4 ov4 = *(const int4*)(O + ro);
        const unsigned short* hu = (const unsigned short*)&hv4;
        const unsigned short* ou = (const unsigned short*)&ov4;
        float x[8];
#pragma unroll
        for (int j = 0; j < 8; j++) x[j] = bf2f(hu[j]) + bf2f(ou[j]);
        float sm = 0.f;
#pragma unroll
        for (int j = 0; j < 8; j++) sm += x[j];
        float mu = wave_sum(sm) * (1.f / HDIM);
        float sq = 0.f;
#pragma unroll
        for (int j = 0; j < 8; j++) { float d = x[j] - mu; sq += d * d; }
        float rs = fast_rsq(wave_sum(sq) * (1.f / HDIM) + 1e-5f);
        float out[8];
#pragma unroll
        for (int j = 0; j < 8; j++) out[j] = (x[j] - mu) * rs * w1v[j] + b1v[j];
        float sm2 = 0.f;
#pragma unroll
        for (int j = 0; j < 8; j++) sm2 += out[j];
        float mu2 = wave_sum(sm2) * (1.f / HDIM);
        float sq2 = 0.f;
#pragma unroll
        for (int j = 0; j < 8; j++) { float d = out[j] - mu2; sq2 += d * d; }
        float rs2 = fast_rsq(wave_sum(sq2) * (1.f / HDIM) + 1e-5f);
        float hn[8];
#pragma unroll
        for (int j = 0; j < 8; j++) {
            float ff = fmaxf(0.f, (out[j] - mu2) * rs2 * w2v[j] + b2v[j]);
            hn[j] = out[j] + ff;
            macc[j] += hn[j];
        }
        if (dstF) {
            float4 o1 = {hn[0], hn[1], hn[2], hn[3]};
            float4 o2 = {hn[4], hn[5], hn[6], hn[7]};
            *(float4*)(dstF + ro) = o1;
            *(float4*)(dstF + ro + 4) = o2;
        }
        if (dst_bf) {
            unsigned q[4];
#pragma unroll
            for (int j = 0; j < 4; j++)
                q[j] = (unsigned)f2bf(hn[2 * j]) | ((unsigned)f2bf(hn[2 * j + 1]) << 16);
            *(int4*)(dst_bf + ro) = *(int4*)q;
        }
    }

    if (msum_next) {
        for (int i = tid; i < HDIM; i += 256) red[i] = 0.f;
        __syncthreads();
#pragma unroll
        for (int j = 0; j < 8; j++) atomicAdd(&red[c0 + j], macc[j]);
        __syncthreads();
        for (int i = tid; i < HDIM; i += 256)
            atomicAdd(&msum_next[b * HDIM + i], red[i]);
    }
}

// ---------------------------------------------------------------------------
extern "C" void kernel_launch(void* const* d_in, const int* in_sizes, int n_in,
                              void* d_out, int out_size, void* d_ws, size_t ws_size,
                              hipStream_t stream)
{
    const float* x   = (const float*)d_in[0];
    const float* Win = (const float*)d_in[1];
    const float* bin = (const float*)d_in[2];
    const float* tmk = (const float*)d_in[3];
    const float* tmv = (const float*)d_in[4];
    const float* tmr = (const float*)d_in[5];
    const float* Wk  = (const float*)d_in[6];
    const float* Wv  = (const float*)d_in[7];
    const float* Wr  = (const float*)d_in[8];
    const float* Wo  = (const float*)d_in[9];
    const float* l1w = (const float*)d_in[10];
    const float* l1b = (const float*)d_in[11];
    const float* l2w = (const float*)d_in[12];
    const float* l2b = (const float*)d_in[13];

    char* ws = (char*)d_ws;
    size_t off = 0;
    auto alloc = [&](size_t bytes) -> char* {
        char* p = ws + off;
        off += (bytes + 255) & ~(size_t)255;
        return p;
    };
    const size_t NTOK = (size_t)BDIM * S_LEN;            // 32768 rows
    const size_t HH = (size_t)HDIM * HDIM;
    // region0: x_bf during input proj, then reused as y_bf
    unsigned short* region0 = (unsigned short*)alloc(NTOK * HDIM * 2);
    unsigned short* x_bf   = region0;
    unsigned short* y_bf   = region0;
    unsigned short* Win_bf = (unsigned short*)alloc((size_t)HDIM * DIN * 2);
    unsigned short* Wo_bf  = (unsigned short*)alloc(NLAYER * HH * 2);
    unsigned short* Wf     = (unsigned short*)alloc(NLAYER * 3 * HH * 2);
    unsigned short* h_bf   = (unsigned short*)alloc(NTOK * HDIM * 2);   // layer-0 h
    unsigned short* h2_bf  = (unsigned short*)alloc(NTOK * HDIM * 2);   // layer-1 h
    unsigned short* s_bf   = (unsigned short*)alloc(NTOK * HDIM * 2);
    unsigned short* r_bf   = (unsigned short*)alloc(NTOK * HDIM * 2);
    unsigned short* o_bf   = (unsigned short*)alloc(NTOK * HDIM * 2);   // Wo out (bf16)
    float*          msum   = (float*)alloc(2 * BDIM * HDIM * 4);
    float*          mbuf   = (float*)alloc(3 * BDIM * HDIM * 4);

    hipMemsetAsync(msum, 0, 2 * BDIM * HDIM * 4, stream);

    // merged head conversions: x, Win, Wo, folded-Wf in ONE launch
    {
        int na4 = (int)(NTOK * DIN / 4);
        int nb4 = (int)((size_t)HDIM * DIN / 4);
        int nc4 = (int)(NLAYER * HH / 4);
        int nf4 = (int)(NLAYER * 3 * HH / 4);
        int tot = na4 + nb4 + nc4 + nf4;
        cvt4_k<<<(tot + 255) / 256, 256, 0, stream>>>(
            x, x_bf, na4, Win, Win_bf, nb4, Wo, Wo_bf, nc4,
            Wk, Wv, Wr, tmk, tmv, tmr, Wf, nf4);
    }

    const float invS = 1.f / S_LEN;

    // h = bf16(x @ W_in^T + b_in)  (+ colsums into msum[0]); NW=4
    gemm2_k<128, 128, 1, 0, DIN, 4, 4><<<1024, 256, 0, stream>>>(
        x_bf, Win_bf, nullptr, nullptr, bin, h_bf, nullptr, msum);

    for (int l = 0; l < NLAYER; l++) {
        const unsigned short* hl = (l == 0) ? h_bf : h2_bf;
        // per-batch mean-bias vectors for k,v,r
        meanbias_k<<<dim3(3, BDIM, 8), 256, 0, stream>>>(
            msum + (size_t)l * BDIM * HDIM, invS,
            Wk + (size_t)l * HH, Wv + (size_t)l * HH, Wr + (size_t)l * HH,
            tmk + l * HDIM, tmv + l * HDIM, tmr + l * HDIM, mbuf);
        // fused k/v/r GEMM (folded weights): s_bf, r_bf — NW=8 (512 threads),
        // 2 blocks/CU, 4 waves/SIMD at the same dbuf counted-vmcnt schedule
        gemm2_k<128, 64, 3, 1, HDIM, 8, 8><<<2048, 512, 0, stream>>>(
            hl,
            Wf + ((size_t)l * 3 + 0) * HH, Wf + ((size_t)l * 3 + 1) * HH,
            Wf + ((size_t)l * 3 + 2) * HH,
            mbuf, s_bf, r_bf, nullptr);
        // wkv scan + y = r*wkv
        scan_k<<<dim3(S_LEN / 64, 1, BDIM), 256, 0, stream>>>(s_bf, r_bf, y_bf);
        // out_pre = bf16(y @ Wo^T), coalesced; NW=4
        gemm2_k<128, 128, 1, 3, HDIM, 4, 4><<<1024, 256, 0, stream>>>(
            y_bf, Wo_bf + (size_t)l * HH, nullptr, nullptr,
            nullptr, o_bf, nullptr, nullptr);
        // LN1 + LN2 + relu + residuals
        lnfuse_k<<<dim3(128, BDIM), 256, 0, stream>>>(
            hl, o_bf, l1w + l * HDIM, l1b + l * HDIM, l2w + l * HDIM, l2b + l * HDIM,
            (l == 0) ? nullptr : (float*)d_out,
            (l == 0) ? h2_bf : nullptr,
            (l == 0) ? (msum + BDIM * HDIM) : nullptr);
    }
}